// Round 2
// baseline (552.622 us; speedup 1.0000x reference)
//
#include <hip/hip_runtime.h>

typedef unsigned short u16;
typedef unsigned int u32;
using bf16x8 = __attribute__((ext_vector_type(8))) __bf16;
using f32x4  = __attribute__((ext_vector_type(4))) float;

#define T_TOK 4096
#define DIMD  1024
#define HIDN  2048
#define NEXP  8

// ---- workspace layout (bytes) ----
#define OFF_CNT  0                          // int[8]
#define OFF_OFFS 64                         // int[9]
#define OFF_TOK  1024                       // int[8][4096]
#define OFF_WGT  (OFF_TOK + NEXP*T_TOK*4)   // float[8][4096]
#define OFF_XB   (1<<20)                    // bf16[4096][1024]
#define SZ_XB    (T_TOK*DIMD*2)
#define OFF_W1T  (OFF_XB + SZ_XB)
#define SZ_W     (NEXP*DIMD*HIDN*2)         // 33554432 B each, [E][N][K] bf16
#define OFF_W3T  (OFF_W1T + SZ_W)
#define OFF_W2T  (OFF_W3T + SZ_W)
#define OFF_H    (OFF_W2T + SZ_W)           // bf16[8192][2048]

__device__ __forceinline__ u16 f2bf(float f) {
    u32 u = __float_as_uint(f);
    u32 r = (u + 0x7fff + ((u >> 16) & 1)) >> 16;
    return (u16)r;
}

// async global->LDS, 16B per lane; lds ptr must be wave-uniform base
__device__ __forceinline__ void gl2lds16(const void* g, void* l) {
    __builtin_amdgcn_global_load_lds(
        (__attribute__((address_space(1))) void*)(g),
        (__attribute__((address_space(3))) void*)(l),
        16, 0, 0);
}

// swizzled frag read: tile rows of 64 bf16 (128B = 8 16B-blocks), block b of row r
// stored at position b ^ (r&7). Frag (row r, sub-k s, quad q) = global k-block s*4+q.
__device__ __forceinline__ bf16x8 ldfrag(const u16* base, int r, int s, int q) {
    int idx = r * 64 + ((((s << 2) | q) ^ (r & 7)) << 3);
    union { uint4 u; bf16x8 b; } c;
    c.u = *(const uint4*)(base + idx);
    return c.b;
}

// ------------------------------------------------------------------ gate
// fp32 inputs: x [T][D], Wg [D][E]. One wave per token.
__global__ __launch_bounds__(256) void gate_kernel(
    const float* __restrict__ x, const float* __restrict__ wg,
    int* __restrict__ cnt, int* __restrict__ tok, float* __restrict__ wgt)
{
    int t = blockIdx.x * 4 + (threadIdx.x >> 6);
    int lane = threadIdx.x & 63;
    float s[8];
#pragma unroll
    for (int e = 0; e < 8; e++) s[e] = 0.f;
    const float* xr = x + (size_t)t * DIMD;
#pragma unroll
    for (int i = 0; i < 16; i++) {
        int d = i * 64 + lane;
        float xv = xr[d];
        float4 w0 = *(const float4*)(wg + d * 8);
        float4 w1 = *(const float4*)(wg + d * 8 + 4);
        s[0] += xv * w0.x; s[1] += xv * w0.y;
        s[2] += xv * w0.z; s[3] += xv * w0.w;
        s[4] += xv * w1.x; s[5] += xv * w1.y;
        s[6] += xv * w1.z; s[7] += xv * w1.w;
    }
#pragma unroll
    for (int e = 0; e < 8; e++)
        for (int off = 32; off; off >>= 1) s[e] += __shfl_xor(s[e], off, 64);
    if (lane == 0) {
        int e0 = 0; float b0 = s[0];
        for (int e = 1; e < 8; e++) if (s[e] > b0) { b0 = s[e]; e0 = e; }
        int e1 = (e0 == 0) ? 1 : 0; float b1 = s[e1];
        for (int e = 0; e < 8; e++) if (e != e0 && s[e] > b1) { b1 = s[e]; e1 = e; }
        float ex = __expf(b1 - b0);          // <= 1
        float w0 = 1.f / (1.f + ex);
        float w1 = ex / (1.f + ex);
        int p0 = atomicAdd(&cnt[e0], 1);
        tok[e0 * T_TOK + p0] = t; wgt[e0 * T_TOK + p0] = w0;
        int p1 = atomicAdd(&cnt[e1], 1);
        tok[e1 * T_TOK + p1] = t; wgt[e1 * T_TOK + p1] = w1;
    }
}

__global__ void offs_kernel(const int* __restrict__ cnt, int* __restrict__ offs)
{
    if (threadIdx.x == 0) {
        int a = 0;
        for (int e = 0; e < 8; e++) { offs[e] = a; a += cnt[e]; }
        offs[8] = a;
    }
}

// ---------------------------------------------------- x fp32 -> bf16
__global__ __launch_bounds__(256) void convx_kernel(
    const float* __restrict__ in, u16* __restrict__ out)
{
    int i = (blockIdx.x * 256 + threadIdx.x) * 4;
    float4 v = *(const float4*)(in + i);
    ushort4 o;
    o.x = f2bf(v.x); o.y = f2bf(v.y); o.z = f2bf(v.z); o.w = f2bf(v.w);
    *(ushort4*)(out + i) = o;
}

// ------------------------------------- weight transpose + fp32->bf16
// in fp32: [E][K][N] -> out bf16: [E][N][K], 64x64 tiles via LDS
__global__ __launch_bounds__(256) void transpose_kernel(
    const float* __restrict__ in, u16* __restrict__ out, int K, int N)
{
    __shared__ u16 t[64 * 72];
    int e = blockIdx.z;
    int n0 = blockIdx.x * 64, k0 = blockIdx.y * 64;
    const float* ip = in + (size_t)e * K * N;
    u16* op = out + (size_t)e * K * N;
    int tid = threadIdx.x;
    int r = tid >> 2, c = (tid & 3) * 16;
    const float4* src = (const float4*)(ip + (size_t)(k0 + r) * N + n0 + c);
    float4 v0 = src[0], v1 = src[1], v2 = src[2], v3 = src[3];
    u16* dstl = t + r * 72 + c;
    dstl[0]  = f2bf(v0.x); dstl[1]  = f2bf(v0.y); dstl[2]  = f2bf(v0.z); dstl[3]  = f2bf(v0.w);
    dstl[4]  = f2bf(v1.x); dstl[5]  = f2bf(v1.y); dstl[6]  = f2bf(v1.z); dstl[7]  = f2bf(v1.w);
    dstl[8]  = f2bf(v2.x); dstl[9]  = f2bf(v2.y); dstl[10] = f2bf(v2.z); dstl[11] = f2bf(v2.w);
    dstl[12] = f2bf(v3.x); dstl[13] = f2bf(v3.y); dstl[14] = f2bf(v3.z); dstl[15] = f2bf(v3.w);
    __syncthreads();
    int n = tid >> 2;
    union { u16 s[16]; uint4 q[2]; } u;
#pragma unroll
    for (int i = 0; i < 16; i++) u.s[i] = t[(c + i) * 72 + n];
    uint4* dst = (uint4*)(op + (size_t)(n0 + n) * K + k0 + c);
    dst[0] = u.q[0]; dst[1] = u.q[1];
}

// ------------------------------------------------------------------ GEMM1
// H[slot] = w * silu(x@W1) * (x@W3), tile 128(M) x 64(N) x 64(K), dual B
__global__ __launch_bounds__(256, 2) void gemm1_kernel(
    const u16* __restrict__ xb, const u16* __restrict__ w1t, const u16* __restrict__ w3t,
    const int* __restrict__ cnt, const int* __restrict__ offs,
    const int* __restrict__ tok, const float* __restrict__ wgt,
    u16* __restrict__ H)
{
    const int e = blockIdx.z, mt = blockIdx.y, nt = blockIdx.x;
    const int ce = cnt[e];
    if (mt * 128 >= ce) return;
    const int base = offs[e];
    const int* tokp = tok + e * T_TOK;

    __shared__ u16 smem[128 * 64 + 64 * 64 + 64 * 64];
    u16* As  = smem;
    u16* B1s = smem + 128 * 64;
    u16* B2s = B1s + 64 * 64;

    const int tid = threadIdx.x;
    const int lane = tid & 63, q = lane >> 4, ln = lane & 15;
    const int wv = tid >> 6;
    const int wm = (wv & 1) * 64, wn = (wv >> 1) * 32;
    const int wbase = tid & ~63;

    f32x4 acc1[4][2], acc2[4][2];
#pragma unroll
    for (int a = 0; a < 4; a++)
#pragma unroll
        for (int b = 0; b < 2; b++) { acc1[a][b] = {0.f,0.f,0.f,0.f}; acc2[a][b] = {0.f,0.f,0.f,0.f}; }

    const u16* w1p = w1t + ((size_t)e * HIDN + nt * 64) * DIMD;
    const u16* w3p = w3t + ((size_t)e * HIDN + nt * 64) * DIMD;

    for (int k0 = 0; k0 < DIMD; k0 += 64) {
        __syncthreads();
#pragma unroll
        for (int i = 0; i < 4; i++) {          // A tile: 128 rows x 128B
            int slot = i * 256 + tid;
            int m = slot >> 3;
            int bk = (slot & 7) ^ (m & 7);
            int mg = mt * 128 + m;
            int trow = (mg < ce) ? tokp[mg] : 0;
            gl2lds16(xb + (size_t)trow * DIMD + k0 + bk * 8, As + (i * 256 + wbase) * 8);
        }
#pragma unroll
        for (int i = 0; i < 2; i++) {          // B tiles: 64 rows x 128B each
            int slot = i * 256 + tid;
            int n = slot >> 3;
            int bk = (slot & 7) ^ (n & 7);
            gl2lds16(w1p + (size_t)n * DIMD + k0 + bk * 8, B1s + (i * 256 + wbase) * 8);
            gl2lds16(w3p + (size_t)n * DIMD + k0 + bk * 8, B2s + (i * 256 + wbase) * 8);
        }
        __syncthreads();
#pragma unroll
        for (int s = 0; s < 2; s++) {
            bf16x8 af[4];
#pragma unroll
            for (int mf = 0; mf < 4; mf++) af[mf] = ldfrag(As, wm + mf * 16 + ln, s, q);
#pragma unroll
            for (int nf = 0; nf < 2; nf++) {
                bf16x8 b1 = ldfrag(B1s, wn + nf * 16 + ln, s, q);
                bf16x8 b2 = ldfrag(B2s, wn + nf * 16 + ln, s, q);
#pragma unroll
                for (int mf = 0; mf < 4; mf++) {
                    acc1[mf][nf] = __builtin_amdgcn_mfma_f32_16x16x32_bf16(af[mf], b1, acc1[mf][nf], 0, 0, 0);
                    acc2[mf][nf] = __builtin_amdgcn_mfma_f32_16x16x32_bf16(af[mf], b2, acc2[mf][nf], 0, 0, 0);
                }
            }
        }
    }

    const float* wr = wgt + e * T_TOK;
#pragma unroll
    for (int mf = 0; mf < 4; mf++) {
#pragma unroll
        for (int r = 0; r < 4; r++) {
            int mg = mt * 128 + wm + mf * 16 + q * 4 + r;
            if (mg < ce) {
                float wv_ = wr[mg];
                size_t hrow = (size_t)(base + mg) * HIDN + nt * 64 + wn;
#pragma unroll
                for (int nf = 0; nf < 2; nf++) {
                    float c1 = acc1[mf][nf][r], c2 = acc2[mf][nf][r];
                    float h = (c1 / (1.f + __expf(-c1))) * c2 * wv_;
                    H[hrow + nf * 16 + ln] = f2bf(h);
                }
            }
        }
    }
}

// ------------------------------------------------------------------ GEMM2
// out[token] += H @ W2 (fp32 atomic scatter), tile 128x128x64
__global__ __launch_bounds__(256, 2) void gemm2_kernel(
    const u16* __restrict__ H, const u16* __restrict__ w2t,
    const int* __restrict__ cnt, const int* __restrict__ offs,
    const int* __restrict__ tok, float* __restrict__ out)
{
    const int e = blockIdx.z, mt = blockIdx.y, nt = blockIdx.x;
    const int ce = cnt[e];
    if (mt * 128 >= ce) return;
    const int base = offs[e];
    const int* tokp = tok + e * T_TOK;

    __shared__ u16 smem[128 * 64 + 128 * 64];
    u16* As = smem;
    u16* Bs = smem + 128 * 64;

    const int tid = threadIdx.x;
    const int lane = tid & 63, q = lane >> 4, ln = lane & 15;
    const int wv = tid >> 6;
    const int wm = (wv & 1) * 64, wn = (wv >> 1) * 64;
    const int wbase = tid & ~63;

    f32x4 av[4][4];
#pragma unroll
    for (int a = 0; a < 4; a++)
#pragma unroll
        for (int b = 0; b < 4; b++) av[a][b] = {0.f,0.f,0.f,0.f};

    const u16* w2p = w2t + ((size_t)e * DIMD + nt * 128) * HIDN;

    for (int k0 = 0; k0 < HIDN; k0 += 64) {
        __syncthreads();
#pragma unroll
        for (int i = 0; i < 4; i++) {
            int slot = i * 256 + tid;
            int m = slot >> 3;
            int bk = (slot & 7) ^ (m & 7);
            int mg = mt * 128 + m;
            int ar = base + ((mg < ce) ? mg : 0);
            gl2lds16(H + (size_t)ar * HIDN + k0 + bk * 8, As + (i * 256 + wbase) * 8);
            gl2lds16(w2p + (size_t)m * HIDN + k0 + bk * 8, Bs + (i * 256 + wbase) * 8);
        }
        __syncthreads();
#pragma unroll
        for (int s = 0; s < 2; s++) {
            bf16x8 af[4], bfr[4];
#pragma unroll
            for (int mf = 0; mf < 4; mf++) af[mf]  = ldfrag(As, wm + mf * 16 + ln, s, q);
#pragma unroll
            for (int nf = 0; nf < 4; nf++) bfr[nf] = ldfrag(Bs, wn + nf * 16 + ln, s, q);
#pragma unroll
            for (int mf = 0; mf < 4; mf++)
#pragma unroll
                for (int nf = 0; nf < 4; nf++)
                    av[mf][nf] = __builtin_amdgcn_mfma_f32_16x16x32_bf16(af[mf], bfr[nf], av[mf][nf], 0, 0, 0);
        }
    }

#pragma unroll
    for (int mf = 0; mf < 4; mf++) {
#pragma unroll
        for (int r = 0; r < 4; r++) {
            int mg = mt * 128 + wm + mf * 16 + q * 4 + r;
            if (mg < ce) {
                int tko = tokp[mg];
                float* orow = out + (size_t)tko * DIMD + nt * 128 + wn;
#pragma unroll
                for (int nf = 0; nf < 4; nf++)
                    atomicAdd(orow + nf * 16 + ln, av[mf][nf][r]);
            }
        }
    }
}

// ------------------------------------------------------------------ launch
extern "C" void kernel_launch(void* const* d_in, const int* in_sizes, int n_in,
                              void* d_out, int out_size, void* d_ws, size_t ws_size,
                              hipStream_t stream)
{
    const float* x  = (const float*)d_in[0];
    const float* wg = (const float*)d_in[1];
    const float* w1 = (const float*)d_in[2];
    const float* w3 = (const float*)d_in[3];
    const float* w2 = (const float*)d_in[4];

    char* ws = (char*)d_ws;
    int*   cnt  = (int*)(ws + OFF_CNT);
    int*   offs = (int*)(ws + OFF_OFFS);
    int*   tok  = (int*)(ws + OFF_TOK);
    float* wgt  = (float*)(ws + OFF_WGT);
    u16*   xb   = (u16*)(ws + OFF_XB);
    u16*   w1t  = (u16*)(ws + OFF_W1T);
    u16*   w3t  = (u16*)(ws + OFF_W3T);
    u16*   w2t  = (u16*)(ws + OFF_W2T);
    u16*   Hbuf = (u16*)(ws + OFF_H);
    float* outp = (float*)d_out;

    hipMemsetAsync(ws + OFF_CNT, 0, 64, stream);
    hipMemsetAsync(d_out, 0, (size_t)T_TOK * DIMD * 4, stream);

    gate_kernel<<<T_TOK / 4, 256, 0, stream>>>(x, wg, cnt, tok, wgt);
    offs_kernel<<<1, 64, 0, stream>>>(cnt, offs);

    convx_kernel<<<(T_TOK * DIMD) / 1024, 256, 0, stream>>>(x, xb);

    transpose_kernel<<<dim3(HIDN / 64, DIMD / 64, NEXP), 256, 0, stream>>>(w1, w1t, DIMD, HIDN);
    transpose_kernel<<<dim3(HIDN / 64, DIMD / 64, NEXP), 256, 0, stream>>>(w3, w3t, DIMD, HIDN);
    transpose_kernel<<<dim3(DIMD / 64, HIDN / 64, NEXP), 256, 0, stream>>>(w2, w2t, HIDN, DIMD);

    gemm1_kernel<<<dim3(HIDN / 64, T_TOK / 128, NEXP), 256, 0, stream>>>(
        xb, w1t, w3t, cnt, offs, tok, wgt, Hbuf);
    gemm2_kernel<<<dim3(DIMD / 128, T_TOK / 128, NEXP), 256, 0, stream>>>(
        Hbuf, w2t, cnt, offs, tok, outp);
}

// Round 3
// 531.688 us; speedup vs baseline: 1.0394x; 1.0394x over previous
//
#include <hip/hip_runtime.h>

typedef unsigned short u16;
typedef unsigned int u32;
using bf16x8 = __attribute__((ext_vector_type(8))) __bf16;
using f32x4  = __attribute__((ext_vector_type(4))) float;

#define T_TOK 4096
#define DIMD  1024
#define HIDN  2048
#define NEXP  8

// ---- workspace layout (bytes) ----
#define OFF_CNT  0                          // int[8]
#define OFF_OFFS 64                         // int[9]
#define OFF_TOK  1024                       // int[8][4096]
#define OFF_WGT  (OFF_TOK + NEXP*T_TOK*4)   // float[8][4096]
#define OFF_XB   (1<<20)                    // bf16[4096][1024]
#define SZ_XB    (T_TOK*DIMD*2)
#define OFF_W1T  (OFF_XB + SZ_XB)
#define SZ_W     (NEXP*DIMD*HIDN*2)         // 33554432 B each, [E][N][K] bf16
#define OFF_W3T  (OFF_W1T + SZ_W)
#define OFF_W2T  (OFF_W3T + SZ_W)
#define OFF_H    (OFF_W2T + SZ_W)           // bf16[8192][2048]

__device__ __forceinline__ u16 f2bf(float f) {
    u32 u = __float_as_uint(f);
    u32 r = (u + 0x7fff + ((u >> 16) & 1)) >> 16;
    return (u16)r;
}

// async global->LDS, 16B per lane; lds ptr must be wave-uniform base
__device__ __forceinline__ void gl2lds16(const void* g, void* l) {
    __builtin_amdgcn_global_load_lds(
        (__attribute__((address_space(1))) void*)(g),
        (__attribute__((address_space(3))) void*)(l),
        16, 0, 0);
}

// swizzled frag read: tile rows of 64 bf16 (128B = 8 16B-blocks), block b of row r
// stored at position b ^ (r&7). Frag (row r, sub-k s, quad q) = global k-block s*4+q.
__device__ __forceinline__ bf16x8 ldfrag(const u16* base, int r, int s, int q) {
    int idx = r * 64 + ((((s << 2) | q) ^ (r & 7)) << 3);
    union { uint4 u; bf16x8 b; } c;
    c.u = *(const uint4*)(base + idx);
    return c.b;
}

// ------------------------------------------------------------------ gate
// fp32 inputs: x [T][D], Wg [D][E]. One wave per token.
// Also converts x -> bf16 xb (fused, x is already in registers).
__global__ __launch_bounds__(256) void gate_kernel(
    const float* __restrict__ x, const float* __restrict__ wg,
    int* __restrict__ cnt, int* __restrict__ tok, float* __restrict__ wgt,
    u16* __restrict__ xb)
{
    int t = blockIdx.x * 4 + (threadIdx.x >> 6);
    int lane = threadIdx.x & 63;
    float s[8];
#pragma unroll
    for (int e = 0; e < 8; e++) s[e] = 0.f;
    const float* xr = x + (size_t)t * DIMD;
    u16* xbr = xb + (size_t)t * DIMD;
#pragma unroll
    for (int i = 0; i < 16; i++) {
        int d = i * 64 + lane;
        float xv = xr[d];
        xbr[d] = f2bf(xv);
        float4 w0 = *(const float4*)(wg + d * 8);
        float4 w1 = *(const float4*)(wg + d * 8 + 4);
        s[0] += xv * w0.x; s[1] += xv * w0.y;
        s[2] += xv * w0.z; s[3] += xv * w0.w;
        s[4] += xv * w1.x; s[5] += xv * w1.y;
        s[6] += xv * w1.z; s[7] += xv * w1.w;
    }
#pragma unroll
    for (int e = 0; e < 8; e++)
        for (int off = 32; off; off >>= 1) s[e] += __shfl_xor(s[e], off, 64);
    if (lane == 0) {
        int e0 = 0; float b0 = s[0];
        for (int e = 1; e < 8; e++) if (s[e] > b0) { b0 = s[e]; e0 = e; }
        int e1 = (e0 == 0) ? 1 : 0; float b1 = s[e1];
        for (int e = 0; e < 8; e++) if (e != e0 && s[e] > b1) { b1 = s[e]; e1 = e; }
        float ex = __expf(b1 - b0);          // <= 1
        float w0 = 1.f / (1.f + ex);
        float w1 = ex / (1.f + ex);
        int p0 = atomicAdd(&cnt[e0], 1);
        tok[e0 * T_TOK + p0] = t; wgt[e0 * T_TOK + p0] = w0;
        int p1 = atomicAdd(&cnt[e1], 1);
        tok[e1 * T_TOK + p1] = t; wgt[e1 * T_TOK + p1] = w1;
    }
}

__global__ void offs_kernel(const int* __restrict__ cnt, int* __restrict__ offs)
{
    if (threadIdx.x == 0) {
        int a = 0;
        for (int e = 0; e < 8; e++) { offs[e] = a; a += cnt[e]; }
        offs[8] = a;
    }
}

// ------------------------------------- weight transpose + fp32->bf16
// in fp32: [E][K][N] -> out bf16: [E][N][K], 64x64 tiles via LDS.
// Two input tensors fused per launch (z<gridDim.z/2 -> inA, else inB).
__global__ __launch_bounds__(256) void transpose2_kernel(
    const float* __restrict__ inA, u16* __restrict__ outA,
    const float* __restrict__ inB, u16* __restrict__ outB,
    int K, int N)
{
    __shared__ u16 t[64 * 72];
    int z = blockIdx.z;
    int e = z & 7;
    const float* in = (z < 8) ? inA : inB;
    u16* out = (z < 8) ? outA : outB;
    int n0 = blockIdx.x * 64, k0 = blockIdx.y * 64;
    const float* ip = in + (size_t)e * K * N;
    u16* op = out + (size_t)e * K * N;
    int tid = threadIdx.x;
    int r = tid >> 2, c = (tid & 3) * 16;
    const float4* src = (const float4*)(ip + (size_t)(k0 + r) * N + n0 + c);
    float4 v0 = src[0], v1 = src[1], v2 = src[2], v3 = src[3];
    u16* dstl = t + r * 72 + c;
    dstl[0]  = f2bf(v0.x); dstl[1]  = f2bf(v0.y); dstl[2]  = f2bf(v0.z); dstl[3]  = f2bf(v0.w);
    dstl[4]  = f2bf(v1.x); dstl[5]  = f2bf(v1.y); dstl[6]  = f2bf(v1.z); dstl[7]  = f2bf(v1.w);
    dstl[8]  = f2bf(v2.x); dstl[9]  = f2bf(v2.y); dstl[10] = f2bf(v2.z); dstl[11] = f2bf(v2.w);
    dstl[12] = f2bf(v3.x); dstl[13] = f2bf(v3.y); dstl[14] = f2bf(v3.z); dstl[15] = f2bf(v3.w);
    __syncthreads();
    int n = tid >> 2;
    union { u16 s[16]; uint4 q[2]; } u;
#pragma unroll
    for (int i = 0; i < 16; i++) u.s[i] = t[(c + i) * 72 + n];
    uint4* dst = (uint4*)(op + (size_t)(n0 + n) * K + k0 + c);
    dst[0] = u.q[0]; dst[1] = u.q[1];
}

__global__ __launch_bounds__(256) void transpose1_kernel(
    const float* __restrict__ in, u16* __restrict__ out, int K, int N)
{
    __shared__ u16 t[64 * 72];
    int e = blockIdx.z;
    int n0 = blockIdx.x * 64, k0 = blockIdx.y * 64;
    const float* ip = in + (size_t)e * K * N;
    u16* op = out + (size_t)e * K * N;
    int tid = threadIdx.x;
    int r = tid >> 2, c = (tid & 3) * 16;
    const float4* src = (const float4*)(ip + (size_t)(k0 + r) * N + n0 + c);
    float4 v0 = src[0], v1 = src[1], v2 = src[2], v3 = src[3];
    u16* dstl = t + r * 72 + c;
    dstl[0]  = f2bf(v0.x); dstl[1]  = f2bf(v0.y); dstl[2]  = f2bf(v0.z); dstl[3]  = f2bf(v0.w);
    dstl[4]  = f2bf(v1.x); dstl[5]  = f2bf(v1.y); dstl[6]  = f2bf(v1.z); dstl[7]  = f2bf(v1.w);
    dstl[8]  = f2bf(v2.x); dstl[9]  = f2bf(v2.y); dstl[10] = f2bf(v2.z); dstl[11] = f2bf(v2.w);
    dstl[12] = f2bf(v3.x); dstl[13] = f2bf(v3.y); dstl[14] = f2bf(v3.z); dstl[15] = f2bf(v3.w);
    __syncthreads();
    int n = tid >> 2;
    union { u16 s[16]; uint4 q[2]; } u;
#pragma unroll
    for (int i = 0; i < 16; i++) u.s[i] = t[(c + i) * 72 + n];
    uint4* dst = (uint4*)(op + (size_t)(n0 + n) * K + k0 + c);
    dst[0] = u.q[0]; dst[1] = u.q[1];
}

// ------------------------------------------------------------------ GEMM1
// H[slot] = w * silu(x@W1) * (x@W3), tile 128(M) x 64(N) x 64(K), dual B
__global__ __launch_bounds__(256, 4) void gemm1_kernel(
    const u16* __restrict__ xb, const u16* __restrict__ w1t, const u16* __restrict__ w3t,
    const int* __restrict__ cnt, const int* __restrict__ offs,
    const int* __restrict__ tok, const float* __restrict__ wgt,
    u16* __restrict__ H)
{
    const int e = blockIdx.z, mt = blockIdx.y, nt = blockIdx.x;
    const int ce = cnt[e];
    if (mt * 128 >= ce) return;
    const int base = offs[e];
    const int* tokp = tok + e * T_TOK;

    __shared__ u16 smem[128 * 64 + 64 * 64 + 64 * 64];
    u16* As  = smem;
    u16* B1s = smem + 128 * 64;
    u16* B2s = B1s + 64 * 64;

    const int tid = threadIdx.x;
    const int lane = tid & 63, q = lane >> 4, ln = lane & 15;
    const int wv = tid >> 6;
    const int wm = (wv & 1) * 64, wn = (wv >> 1) * 32;
    const int wbase = tid & ~63;

    // hoist token-row addresses for the A staging (k-invariant)
    const u16* arow[4];
#pragma unroll
    for (int i = 0; i < 4; i++) {
        int slot = i * 256 + tid;
        int m = slot >> 3;
        int bk = (slot & 7) ^ (m & 7);
        int mg = mt * 128 + m;
        int trow = (mg < ce) ? tokp[mg] : 0;
        arow[i] = xb + (size_t)trow * DIMD + bk * 8;
    }

    f32x4 acc1[4][2], acc2[4][2];
#pragma unroll
    for (int a = 0; a < 4; a++)
#pragma unroll
        for (int b = 0; b < 2; b++) { acc1[a][b] = {0.f,0.f,0.f,0.f}; acc2[a][b] = {0.f,0.f,0.f,0.f}; }

    const u16* w1p = w1t + ((size_t)e * HIDN + nt * 64) * DIMD;
    const u16* w3p = w3t + ((size_t)e * HIDN + nt * 64) * DIMD;

    for (int k0 = 0; k0 < DIMD; k0 += 64) {
        __syncthreads();
#pragma unroll
        for (int i = 0; i < 4; i++)            // A tile: 128 rows x 128B
            gl2lds16(arow[i] + k0, As + (i * 256 + wbase) * 8);
#pragma unroll
        for (int i = 0; i < 2; i++) {          // B tiles: 64 rows x 128B each
            int slot = i * 256 + tid;
            int n = slot >> 3;
            int bk = (slot & 7) ^ (n & 7);
            gl2lds16(w1p + (size_t)n * DIMD + k0 + bk * 8, B1s + (i * 256 + wbase) * 8);
            gl2lds16(w3p + (size_t)n * DIMD + k0 + bk * 8, B2s + (i * 256 + wbase) * 8);
        }
        __syncthreads();
#pragma unroll
        for (int s = 0; s < 2; s++) {
            bf16x8 af[4];
#pragma unroll
            for (int mf = 0; mf < 4; mf++) af[mf] = ldfrag(As, wm + mf * 16 + ln, s, q);
#pragma unroll
            for (int nf = 0; nf < 2; nf++) {
                bf16x8 b1 = ldfrag(B1s, wn + nf * 16 + ln, s, q);
                bf16x8 b2 = ldfrag(B2s, wn + nf * 16 + ln, s, q);
#pragma unroll
                for (int mf = 0; mf < 4; mf++) {
                    acc1[mf][nf] = __builtin_amdgcn_mfma_f32_16x16x32_bf16(af[mf], b1, acc1[mf][nf], 0, 0, 0);
                    acc2[mf][nf] = __builtin_amdgcn_mfma_f32_16x16x32_bf16(af[mf], b2, acc2[mf][nf], 0, 0, 0);
                }
            }
        }
    }

    const float* wr = wgt + e * T_TOK;
#pragma unroll
    for (int mf = 0; mf < 4; mf++) {
#pragma unroll
        for (int r = 0; r < 4; r++) {
            int mg = mt * 128 + wm + mf * 16 + q * 4 + r;
            if (mg < ce) {
                float wv_ = wr[mg];
                size_t hrow = (size_t)(base + mg) * HIDN + nt * 64 + wn;
#pragma unroll
                for (int nf = 0; nf < 2; nf++) {
                    float c1 = acc1[mf][nf][r], c2 = acc2[mf][nf][r];
                    float h = (c1 / (1.f + __expf(-c1))) * c2 * wv_;
                    H[hrow + nf * 16 + ln] = f2bf(h);
                }
            }
        }
    }
}

// ------------------------------------------------------------------ GEMM2
// out[token] += H @ W2 (fp32 atomic scatter), tile 128x128, K split in 2
__global__ __launch_bounds__(256, 4) void gemm2_kernel(
    const u16* __restrict__ H, const u16* __restrict__ w2t,
    const int* __restrict__ cnt, const int* __restrict__ offs,
    const int* __restrict__ tok, float* __restrict__ out)
{
    const int e = blockIdx.z & 7, kh = blockIdx.z >> 3;
    const int mt = blockIdx.y, nt = blockIdx.x;
    const int ce = cnt[e];
    if (mt * 128 >= ce) return;
    const int base = offs[e];
    const int* tokp = tok + e * T_TOK;

    __shared__ u16 smem[128 * 64 + 128 * 64];
    u16* As = smem;
    u16* Bs = smem + 128 * 64;

    const int tid = threadIdx.x;
    const int lane = tid & 63, q = lane >> 4, ln = lane & 15;
    const int wv = tid >> 6;
    const int wm = (wv & 1) * 64, wn = (wv >> 1) * 64;
    const int wbase = tid & ~63;

    // hoist k-invariant staging addresses
    const u16* arow[4];
    const u16* brow[4];
    const u16* w2p = w2t + ((size_t)e * DIMD + nt * 128) * HIDN;
#pragma unroll
    for (int i = 0; i < 4; i++) {
        int slot = i * 256 + tid;
        int m = slot >> 3;
        int bk = (slot & 7) ^ (m & 7);
        int mg = mt * 128 + m;
        int ar = base + ((mg < ce) ? mg : 0);
        arow[i] = H + (size_t)ar * HIDN + bk * 8;
        brow[i] = w2p + (size_t)m * HIDN + bk * 8;
    }

    f32x4 av[4][4];
#pragma unroll
    for (int a = 0; a < 4; a++)
#pragma unroll
        for (int b = 0; b < 4; b++) av[a][b] = {0.f,0.f,0.f,0.f};

    const int kbeg = kh * (HIDN / 2), kend = kbeg + HIDN / 2;
    for (int k0 = kbeg; k0 < kend; k0 += 64) {
        __syncthreads();
#pragma unroll
        for (int i = 0; i < 4; i++) {
            gl2lds16(arow[i] + k0, As + (i * 256 + wbase) * 8);
            gl2lds16(brow[i] + k0, Bs + (i * 256 + wbase) * 8);
        }
        __syncthreads();
#pragma unroll
        for (int s = 0; s < 2; s++) {
            bf16x8 af[4], bfr[4];
#pragma unroll
            for (int mf = 0; mf < 4; mf++) af[mf]  = ldfrag(As, wm + mf * 16 + ln, s, q);
#pragma unroll
            for (int nf = 0; nf < 4; nf++) bfr[nf] = ldfrag(Bs, wn + nf * 16 + ln, s, q);
#pragma unroll
            for (int mf = 0; mf < 4; mf++)
#pragma unroll
                for (int nf = 0; nf < 4; nf++)
                    av[mf][nf] = __builtin_amdgcn_mfma_f32_16x16x32_bf16(af[mf], bfr[nf], av[mf][nf], 0, 0, 0);
        }
    }

#pragma unroll
    for (int mf = 0; mf < 4; mf++) {
#pragma unroll
        for (int r = 0; r < 4; r++) {
            int mg = mt * 128 + wm + mf * 16 + q * 4 + r;
            if (mg < ce) {
                int tko = tokp[mg];
                float* orow = out + (size_t)tko * DIMD + nt * 128 + wn;
#pragma unroll
                for (int nf = 0; nf < 4; nf++)
                    atomicAdd(orow + nf * 16 + ln, av[mf][nf][r]);
            }
        }
    }
}

// ------------------------------------------------------------------ launch
extern "C" void kernel_launch(void* const* d_in, const int* in_sizes, int n_in,
                              void* d_out, int out_size, void* d_ws, size_t ws_size,
                              hipStream_t stream)
{
    const float* x  = (const float*)d_in[0];
    const float* wg = (const float*)d_in[1];
    const float* w1 = (const float*)d_in[2];
    const float* w3 = (const float*)d_in[3];
    const float* w2 = (const float*)d_in[4];

    char* ws = (char*)d_ws;
    int*   cnt  = (int*)(ws + OFF_CNT);
    int*   offs = (int*)(ws + OFF_OFFS);
    int*   tok  = (int*)(ws + OFF_TOK);
    float* wgt  = (float*)(ws + OFF_WGT);
    u16*   xb   = (u16*)(ws + OFF_XB);
    u16*   w1t  = (u16*)(ws + OFF_W1T);
    u16*   w3t  = (u16*)(ws + OFF_W3T);
    u16*   w2t  = (u16*)(ws + OFF_W2T);
    u16*   Hbuf = (u16*)(ws + OFF_H);
    float* outp = (float*)d_out;

    hipMemsetAsync(ws + OFF_CNT, 0, 64, stream);
    hipMemsetAsync(d_out, 0, (size_t)T_TOK * DIMD * 4, stream);

    gate_kernel<<<T_TOK / 4, 256, 0, stream>>>(x, wg, cnt, tok, wgt, xb);
    offs_kernel<<<1, 64, 0, stream>>>(cnt, offs);

    // W1 & W3: [E][1024][2048] -> [E][2048][1024] bf16, fused (z<8: W1, z>=8: W3)
    transpose2_kernel<<<dim3(HIDN / 64, DIMD / 64, 16), 256, 0, stream>>>(
        w1, w1t, w3, w3t, DIMD, HIDN);
    // W2: [E][2048][1024] -> [E][1024][2048] bf16
    transpose1_kernel<<<dim3(DIMD / 64, HIDN / 64, NEXP), 256, 0, stream>>>(
        w2, w2t, HIDN, DIMD);

    gemm1_kernel<<<dim3(HIDN / 64, T_TOK / 128, NEXP), 256, 0, stream>>>(
        xb, w1t, w3t, cnt, offs, tok, wgt, Hbuf);
    gemm2_kernel<<<dim3(DIMD / 128, T_TOK / 128, NEXP * 2), 256, 0, stream>>>(
        Hbuf, w2t, cnt, offs, tok, outp);
}